// Round 6
// baseline (34.886 us; speedup 1.0000x reference)
//
#include <hip/hip_runtime.h>
#include <math.h>

#define NB 8
#define NQ 32
#define NK 32
#define DIM 256

struct c32 { float x, y; };
__device__ __forceinline__ c32 cmul(c32 a, c32 b) {
    return { a.x*b.x - a.y*b.y, a.x*b.y + a.y*b.x };
}

// ---------------------------------------------------------------------------
// Compile-time GF(2) bookkeeping for the CNOT layers (verified rounds 3-5).
// ---------------------------------------------------------------------------
struct Maps { unsigned char m[6][8]; unsigned char r[6][8]; unsigned char fin[8]; };

constexpr unsigned gstep(int rep, unsigned y, int i) {
    int tgt = (i + 1 + rep) % 8;
    return y ^ (((y >> (7 - i)) & 1u) << (7 - tgt));
}
constexpr unsigned Lmap(int rep, unsigned x) {
    unsigned y = x;
    for (int i = 7; i >= 0; --i) y = gstep(rep, y, i);
    return y;
}
constexpr unsigned Linvmap(int rep, unsigned x) {
    unsigned y = x;
    for (int i = 0; i < 8; ++i) y = gstep(rep, y, i);
    return y;
}
constexpr Maps make_maps() {
    Maps mp{};
    unsigned Mc[8], Mic[8];
    for (int j2 = 0; j2 < 8; ++j2) { Mc[j2] = 1u << j2; Mic[j2] = 1u << j2; }
    for (int rep = 0; rep < 6; ++rep) {
        for (int bb = 0; bb < 8; ++bb) {
            mp.m[rep][bb] = (unsigned char)Mc[bb];
            unsigned row = 0;
            for (int k = 0; k < 8; ++k) row |= ((Mic[k] >> bb) & 1u) << k;
            mp.r[rep][bb] = (unsigned char)row;
        }
        unsigned nM[8], nMi[8];
        for (int j2 = 0; j2 < 8; ++j2) {
            unsigned v = Lmap(rep, 1u << j2), acc = 0;
            for (int k = 0; k < 8; ++k) if ((v >> k) & 1u) acc ^= Mc[k];
            nM[j2]  = acc;
            nMi[j2] = Linvmap(rep, Mic[j2]);
        }
        for (int j2 = 0; j2 < 8; ++j2) { Mc[j2] = nM[j2]; Mic[j2] = nMi[j2]; }
    }
    for (int j2 = 0; j2 < 8; ++j2) mp.fin[j2] = (unsigned char)Mic[j2];
    return mp;
}
constexpr Maps MAPS = make_maps();

// vs layout: float2 element index ((b*16 + (k>>1))*256 + d)*2 + (k&1)
// -> combine lane d reads float4 (k pair) perfectly coalesced across lanes.

// ---------------------------------------------------------------------------
// Single kernel, 256 blocks x 256 threads. Block = (b = blockIdx&7, j = blockIdx>>3)
// so each batch's 32 blocks land on one XCD under round-robin dispatch.
// Phase 1: wave0 sims state (b,kst=j) -> vs (global);
//          wave1 computes attn coeffs for (b,q=j) -> LDS.
// Sync:    release atomicAdd(ctr[b]); lane0 acquire-polls ctr[b]==32.
//          (All 256 blocks co-resident at 1/CU; phase1 precedes any wait ->
//           no deadlock; poll window = inter-block skew only.)
// Phase 2: combine for (b,q=j) -> out.
// ---------------------------------------------------------------------------
__global__ __launch_bounds__(256) void fused_kernel(
        const float* __restrict__ query, const float* __restrict__ key,
        const float* __restrict__ value, const float* __restrict__ v_param,
        const float* __restrict__ qk_param, const float* __restrict__ attn_param,
        float2* __restrict__ vs, unsigned* __restrict__ ctr,
        float* __restrict__ out) {
    const int bid = blockIdx.x;
    const int b   = bid & 7;
    const int j   = bid >> 3;
    const int s   = b * 32 + j;          // logical state / (b,q) id
    const int t   = threadIdx.x;
    const int ln  = t & 63;

    __shared__ float2 U[48][4];
    __shared__ float2 coefL[33];
    __shared__ float prob[256];

    if (t < 64) {
        // ================= wave 0: v-sim for state (b, kst=j) =================
        if (ln < 48) {                       // U matrices, built by this wave
            int rep = ln >> 3, w = ln & 7;
            float a   = v_param[(rep*3 + 0)*8 + w];
            float bb2 = v_param[(rep*3 + 1)*8 + w];
            float c   = v_param[(rep*3 + 2)*8 + w];
            float sb, cb;     __sincosf(bb2*0.5f, &sb, &cb);
            float sapc, capc; __sincosf((a + c)*0.5f, &sapc, &capc);
            float samc, camc; __sincosf((a - c)*0.5f, &samc, &camc);
            U[ln][0] = make_float2( cb*capc, -cb*sapc);
            U[ln][1] = make_float2(-sb*camc, -sb*samc);
            U[ln][2] = make_float2( sb*camc, -sb*samc);
            U[ln][3] = make_float2( cb*capc,  cb*sapc);
        }
        // initial RY product state
        float cv[8], sv[8];
        #pragma unroll
        for (int i = 0; i < 8; ++i) __sincosf(value[s*8 + i]*0.5f, &sv[i], &cv[i]);
        float common = 1.f;
        #pragma unroll
        for (int i = 0; i < 6; ++i)
            common *= ((ln >> (5 - i)) & 1) ? sv[i] : cv[i];
        float2 amp[4];
        amp[0] = make_float2(common*cv[6]*cv[7], 0.f);
        amp[1] = make_float2(common*cv[6]*sv[7], 0.f);
        amp[2] = make_float2(common*sv[6]*cv[7], 0.f);
        amp[3] = make_float2(common*sv[6]*sv[7], 0.f);

        // 48-gate chain, barrier-free (verified r3-r5)
        #pragma unroll
        for (int rep = 0; rep < 6; ++rep) {
            #pragma unroll
            for (int w = 0; w < 8; ++w) {
                const int g = rep*8 + w;
                const unsigned mm = MAPS.m[rep][7 - w];
                const unsigned rb = MAPS.r[rep][7 - w];
                const unsigned lm = mm >> 2;
                const unsigned sm = mm & 3;
                const float2 u00 = U[g][0], u01 = U[g][1];
                const float2 u10 = U[g][2], u11 = U[g][3];
                float2 P[4];
                if (sm == 0)      { P[0]=amp[0]; P[1]=amp[1]; P[2]=amp[2]; P[3]=amp[3]; }
                else if (sm == 1) { P[0]=amp[1]; P[1]=amp[0]; P[2]=amp[3]; P[3]=amp[2]; }
                else if (sm == 2) { P[0]=amp[2]; P[1]=amp[3]; P[2]=amp[0]; P[3]=amp[1]; }
                else              { P[0]=amp[3]; P[1]=amp[2]; P[2]=amp[1]; P[3]=amp[0]; }
                if (lm) {
                    #pragma unroll
                    for (int r2 = 0; r2 < 4; ++r2) {
                        P[r2].x = __shfl_xor(P[r2].x, (int)lm);
                        P[r2].y = __shfl_xor(P[r2].y, (int)lm);
                    }
                }
                const unsigned hx = __popc((unsigned)(ln << 2) & rb) & 1u;
                float2 na[4];
                #pragma unroll
                for (int r2 = 0; r2 < 4; ++r2) {
                    const bool h = (hx ^ (__popc((unsigned)r2 & rb) & 1u)) != 0u;
                    const float2 uo = h ? u11 : u00;
                    const float2 up = h ? u10 : u01;
                    na[r2].x = uo.x*amp[r2].x - uo.y*amp[r2].y + up.x*P[r2].x - up.y*P[r2].y;
                    na[r2].y = uo.x*amp[r2].y + uo.y*amp[r2].x + up.x*P[r2].y + up.y*P[r2].x;
                }
                #pragma unroll
                for (int r2 = 0; r2 < 4; ++r2) amp[r2] = na[r2];
            }
        }
        // scatter-store through Minv_final into k-pair-interleaved layout
        unsigned c0 = 0;
        #pragma unroll
        for (int kk = 0; kk < 6; ++kk)
            c0 ^= ((ln >> kk) & 1) ? (unsigned)MAPS.fin[kk + 2] : 0u;
        const int kst = j;
        float2* base = vs + ((size_t)(b*16 + (kst >> 1)) * 256) * 2 + (kst & 1);
        #pragma unroll
        for (int r2 = 0; r2 < 4; ++r2) {
            unsigned c = c0 ^ ((r2 & 1) ? (unsigned)MAPS.fin[0] : 0u)
                            ^ ((r2 & 2) ? (unsigned)MAPS.fin[1] : 0u);
            base[c*2] = amp[r2];
        }
    } else if (t < 128) {
        // ================= wave 1: attention coefficients for (b, q=j) =========
        const int k = ln >> 1, h = ln & 1;
        c32 f = { 1.f, 0.f };
        #pragma unroll
        for (int ii = 0; ii < 4; ++ii) {
            const int i = h*4 + ii;
            float qi  = query[(b*NQ + j)*8 + i];
            float ki  = key[(b*NK + k)*8 + i];
            float phi = attn_param[i] + ((i > 0) ? attn_param[8 + i - 1] : 0.f);
            float Th  = phi + qk_param[8 + i] - ki;
            float gam = qk_param[i] * 0.5f;
            c32 fi = {  __cosf(gam) * __cosf((Th + qi)*0.5f),
                       -__sinf(gam) * __cosf((Th - qi)*0.5f) };
            f = cmul(f, fi);
        }
        {   // combine the two 4-factor halves
            c32 o2 = { __shfl_xor(f.x, 1), __shfl_xor(f.y, 1) };
            f = cmul(f, o2);
        }
        // compact: lane ln<32 grabs f for k=ln (lives at lane 2*ln)
        float fx = __shfl(f.x, 2*ln);
        float fy = __shfl(f.y, 2*ln);
        if (ln < 32) {
            const int kk = ln;
            float h7 = attn_param[15] * 0.5f;
            float s7 = __sinf(h7), c7 = __cosf(h7);
            c32 a0 = { -s7*fx, -s7*fy };
            c32 a1 = {  c7*fx,  c7*fy };
            c32 acc = a0;                      // backward inclusive product scan
            #pragma unroll
            for (int off = 1; off < 32; off <<= 1) {
                c32 v = { __shfl_down(acc.x, off), __shfl_down(acc.y, off) };
                if (kk + off < 32) acc = cmul(acc, v);
            }
            c32 S = { __shfl_down(acc.x, 1), __shfl_down(acc.y, 1) };
            if (kk == 31) { S.x = 1.f; S.y = 0.f; }
            c32 cf = cmul(S, a1);
            coefL[kk] = make_float2(cf.x, cf.y);
            if (kk == 0) coefL[32] = make_float2(acc.x, acc.y);  // total
        }
    }
    __syncthreads();                          // phase-1 results visible

    if (t == 0) {
        __threadfence();                      // vs -> visible device-wide
        __hip_atomic_fetch_add(&ctr[b*32], 1u, __ATOMIC_RELEASE,
                               __HIP_MEMORY_SCOPE_AGENT);
        while (__hip_atomic_load(&ctr[b*32], __ATOMIC_ACQUIRE,
                                 __HIP_MEMORY_SCOPE_AGENT) < 32u)
            __builtin_amdgcn_s_sleep(8);
    }
    __syncthreads();                          // batch b fully staged

    // ================= phase 2: combine for (b, q=j) =================
    {
        const float4* vb4 = reinterpret_cast<const float4*>(
            vs + ((size_t)b*16) * 512);          // b's panel, float2 units
        c32 vn = { 0.f, 0.f };
        #pragma unroll
        for (int k2 = 0; k2 < 16; ++k2) {
            float4 v2 = vb4[k2*256 + t];         // {k=2k2 (x,y), k=2k2+1 (x,y)}
            float2 cfa = coefL[2*k2], cfb = coefL[2*k2 + 1];
            vn.x += cfa.x*v2.x - cfa.y*v2.y + cfb.x*v2.z - cfb.y*v2.w;
            vn.y += cfa.x*v2.y + cfa.y*v2.x + cfb.x*v2.w + cfb.y*v2.z;
        }
        if (t == 0) { vn.x += coefL[32].x; vn.y += coefL[32].y; }
        prob[t] = vn.x*vn.x + vn.y*vn.y;
    }
    __syncthreads();

    // sign expectation per wire
    {
        const int gg = t >> 5, l = t & 31;
        float sp = 0.f, ss = 0.f;
        #pragma unroll
        for (int j2 = 0; j2 < 8; ++j2) {
            int d2 = l + 32*j2;
            float p = prob[d2];
            sp += p;
            ss += ((d2 >> (7 - gg)) & 1) ? -p : p;
        }
        #pragma unroll
        for (int off = 1; off < 32; off <<= 1) {
            sp += __shfl_xor(sp, off);
            ss += __shfl_xor(ss, off);
        }
        if (l == 0) out[(b*NQ + j)*8 + gg] = ss / sp;
    }
}

extern "C" void kernel_launch(void* const* d_in, const int* in_sizes, int n_in,
                              void* d_out, int out_size, void* d_ws, size_t ws_size,
                              hipStream_t stream) {
    const float* query      = (const float*)d_in[0];
    const float* key        = (const float*)d_in[1];
    const float* value      = (const float*)d_in[2];
    const float* v_param    = (const float*)d_in[3];
    const float* qk_param   = (const float*)d_in[4];
    const float* attn_param = (const float*)d_in[5];

    float2*   vs  = (float2*)d_ws;                                   // 512 KB
    unsigned* ctr = (unsigned*)((char*)d_ws + (size_t)512*1024);     // +1 KB
    float*    out = (float*)d_out;

    hipMemsetAsync(ctr, 0, NB * 128, stream);   // reset flags every call
    fused_kernel<<<NB*NK, 256, 0, stream>>>(query, key, value, v_param,
                                            qk_param, attn_param, vs, ctr, out);
}

// Round 7
// 21.166 us; speedup vs baseline: 1.6482x; 1.6482x over previous
//
#include <hip/hip_runtime.h>
#include <math.h>

#define NB 8
#define NQ 32
#define NK 32
#define DIM 256

struct c32 { float x, y; };
__device__ __forceinline__ c32 cmul(c32 a, c32 b) {
    return { a.x*b.x - a.y*b.y, a.x*b.y + a.y*b.x };
}

// System-scope (L3-coherent, cross-XCD) relaxed 8-byte access; no cache ops.
__device__ __forceinline__ void st_sys(float2* p, float2 v) {
    unsigned long long u = __builtin_bit_cast(unsigned long long, v);
    __hip_atomic_store((unsigned long long*)p, u, __ATOMIC_RELAXED,
                       __HIP_MEMORY_SCOPE_SYSTEM);
}
__device__ __forceinline__ float2 ld_sys(const float2* p) {
    unsigned long long u = __hip_atomic_load((const unsigned long long*)p,
                                             __ATOMIC_RELAXED,
                                             __HIP_MEMORY_SCOPE_SYSTEM);
    return __builtin_bit_cast(float2, u);
}

// Ready-flags: zero-initialized at module load; self-resetting each call
// (32 produce-adds + 32 consume-adds per batch; 64th arriver stores 0), so
// every kernel_launch starts AND ends with g_ctr == 0 — deterministic.
__device__ unsigned g_ctr[NB];

// ---------------------------------------------------------------------------
// Compile-time GF(2) bookkeeping for the CNOT layers (verified rounds 3-6).
// ---------------------------------------------------------------------------
struct Maps { unsigned char m[6][8]; unsigned char r[6][8]; unsigned char fin[8]; };

constexpr unsigned gstep(int rep, unsigned y, int i) {
    int tgt = (i + 1 + rep) % 8;
    return y ^ (((y >> (7 - i)) & 1u) << (7 - tgt));
}
constexpr unsigned Lmap(int rep, unsigned x) {
    unsigned y = x;
    for (int i = 7; i >= 0; --i) y = gstep(rep, y, i);
    return y;
}
constexpr unsigned Linvmap(int rep, unsigned x) {
    unsigned y = x;
    for (int i = 0; i < 8; ++i) y = gstep(rep, y, i);
    return y;
}
constexpr Maps make_maps() {
    Maps mp{};
    unsigned Mc[8], Mic[8];
    for (int j2 = 0; j2 < 8; ++j2) { Mc[j2] = 1u << j2; Mic[j2] = 1u << j2; }
    for (int rep = 0; rep < 6; ++rep) {
        for (int bb = 0; bb < 8; ++bb) {
            mp.m[rep][bb] = (unsigned char)Mc[bb];
            unsigned row = 0;
            for (int k = 0; k < 8; ++k) row |= ((Mic[k] >> bb) & 1u) << k;
            mp.r[rep][bb] = (unsigned char)row;
        }
        unsigned nM[8], nMi[8];
        for (int j2 = 0; j2 < 8; ++j2) {
            unsigned v = Lmap(rep, 1u << j2), acc = 0;
            for (int k = 0; k < 8; ++k) if ((v >> k) & 1u) acc ^= Mc[k];
            nM[j2]  = acc;
            nMi[j2] = Linvmap(rep, Mic[j2]);
        }
        for (int j2 = 0; j2 < 8; ++j2) { Mc[j2] = nM[j2]; Mic[j2] = nMi[j2]; }
    }
    for (int j2 = 0; j2 < 8; ++j2) mp.fin[j2] = (unsigned char)Mic[j2];
    return mp;
}
constexpr Maps MAPS = make_maps();

// vs layout: float2 element index ((b*16 + (k>>1))*256 + d)*2 + (k&1)

// ---------------------------------------------------------------------------
// Single kernel, 256 blocks x 256 threads. Block = (b = bid&7, j = bid>>3).
// Phase 1: wave0 sims state (b,k=j) -> vs via sc1 stores (L3-resident);
//          wave1 computes attn coeffs for (b,q=j) -> LDS.
// Sync:    vmcnt(0); relaxed system atomicAdd(g_ctr[b]); relaxed spin >=32.
//          (No release/acquire -> no L2 writeback/invalidate storms.)
// Phase 2: combine for (b,q=j) via sc1 loads -> out. Ticket reset to 0.
// ---------------------------------------------------------------------------
__global__ __launch_bounds__(256) void fused_kernel(
        const float* __restrict__ query, const float* __restrict__ key,
        const float* __restrict__ value, const float* __restrict__ v_param,
        const float* __restrict__ qk_param, const float* __restrict__ attn_param,
        float2* __restrict__ vs, float* __restrict__ out) {
    const int bid = blockIdx.x;
    const int b   = bid & 7;
    const int j   = bid >> 3;
    const int s   = b * 32 + j;          // logical state / (b,q) id
    const int t   = threadIdx.x;
    const int ln  = t & 63;

    __shared__ float2 U[48][4];
    __shared__ float2 coefL[33];
    __shared__ float prob[256];

    if (t < 64) {
        // ================= wave 0: v-sim for state (b, kst=j) =================
        if (ln < 48) {                       // U matrices, built by this wave
            int rep = ln >> 3, w = ln & 7;
            float a   = v_param[(rep*3 + 0)*8 + w];
            float bb2 = v_param[(rep*3 + 1)*8 + w];
            float c   = v_param[(rep*3 + 2)*8 + w];
            float sb, cb;     __sincosf(bb2*0.5f, &sb, &cb);
            float sapc, capc; __sincosf((a + c)*0.5f, &sapc, &capc);
            float samc, camc; __sincosf((a - c)*0.5f, &samc, &camc);
            U[ln][0] = make_float2( cb*capc, -cb*sapc);
            U[ln][1] = make_float2(-sb*camc, -sb*samc);
            U[ln][2] = make_float2( sb*camc, -sb*samc);
            U[ln][3] = make_float2( cb*capc,  cb*sapc);
        }
        // initial RY product state
        float cv[8], sv[8];
        #pragma unroll
        for (int i = 0; i < 8; ++i) __sincosf(value[s*8 + i]*0.5f, &sv[i], &cv[i]);
        float common = 1.f;
        #pragma unroll
        for (int i = 0; i < 6; ++i)
            common *= ((ln >> (5 - i)) & 1) ? sv[i] : cv[i];
        float2 amp[4];
        amp[0] = make_float2(common*cv[6]*cv[7], 0.f);
        amp[1] = make_float2(common*cv[6]*sv[7], 0.f);
        amp[2] = make_float2(common*sv[6]*cv[7], 0.f);
        amp[3] = make_float2(common*sv[6]*sv[7], 0.f);

        // 48-gate chain, barrier-free (verified r3-r6)
        #pragma unroll
        for (int rep = 0; rep < 6; ++rep) {
            #pragma unroll
            for (int w = 0; w < 8; ++w) {
                const int g = rep*8 + w;
                const unsigned mm = MAPS.m[rep][7 - w];
                const unsigned rb = MAPS.r[rep][7 - w];
                const unsigned lm = mm >> 2;
                const unsigned sm = mm & 3;
                const float2 u00 = U[g][0], u01 = U[g][1];
                const float2 u10 = U[g][2], u11 = U[g][3];
                float2 P[4];
                if (sm == 0)      { P[0]=amp[0]; P[1]=amp[1]; P[2]=amp[2]; P[3]=amp[3]; }
                else if (sm == 1) { P[0]=amp[1]; P[1]=amp[0]; P[2]=amp[3]; P[3]=amp[2]; }
                else if (sm == 2) { P[0]=amp[2]; P[1]=amp[3]; P[2]=amp[0]; P[3]=amp[1]; }
                else              { P[0]=amp[3]; P[1]=amp[2]; P[2]=amp[1]; P[3]=amp[0]; }
                if (lm) {
                    #pragma unroll
                    for (int r2 = 0; r2 < 4; ++r2) {
                        P[r2].x = __shfl_xor(P[r2].x, (int)lm);
                        P[r2].y = __shfl_xor(P[r2].y, (int)lm);
                    }
                }
                const unsigned hx = __popc((unsigned)(ln << 2) & rb) & 1u;
                float2 na[4];
                #pragma unroll
                for (int r2 = 0; r2 < 4; ++r2) {
                    const bool h = (hx ^ (__popc((unsigned)r2 & rb) & 1u)) != 0u;
                    const float2 uo = h ? u11 : u00;
                    const float2 up = h ? u10 : u01;
                    na[r2].x = uo.x*amp[r2].x - uo.y*amp[r2].y + up.x*P[r2].x - up.y*P[r2].y;
                    na[r2].y = uo.x*amp[r2].y + uo.y*amp[r2].x + up.x*P[r2].y + up.y*P[r2].x;
                }
                #pragma unroll
                for (int r2 = 0; r2 < 4; ++r2) amp[r2] = na[r2];
            }
        }
        // scatter-store through Minv_final into k-pair-interleaved layout (sc1)
        unsigned c0 = 0;
        #pragma unroll
        for (int kk = 0; kk < 6; ++kk)
            c0 ^= ((ln >> kk) & 1) ? (unsigned)MAPS.fin[kk + 2] : 0u;
        const int kst = j;
        float2* base = vs + ((size_t)(b*16 + (kst >> 1)) * 256) * 2 + (kst & 1);
        #pragma unroll
        for (int r2 = 0; r2 < 4; ++r2) {
            unsigned c = c0 ^ ((r2 & 1) ? (unsigned)MAPS.fin[0] : 0u)
                            ^ ((r2 & 2) ? (unsigned)MAPS.fin[1] : 0u);
            st_sys(&base[c*2], amp[r2]);
        }
    } else if (t < 128) {
        // ================= wave 1: attention coefficients for (b, q=j) =========
        const int k = ln >> 1, h = ln & 1;
        c32 f = { 1.f, 0.f };
        #pragma unroll
        for (int ii = 0; ii < 4; ++ii) {
            const int i = h*4 + ii;
            float qi  = query[(b*NQ + j)*8 + i];
            float ki  = key[(b*NK + k)*8 + i];
            float phi = attn_param[i] + ((i > 0) ? attn_param[8 + i - 1] : 0.f);
            float Th  = phi + qk_param[8 + i] - ki;
            float gam = qk_param[i] * 0.5f;
            c32 fi = {  __cosf(gam) * __cosf((Th + qi)*0.5f),
                       -__sinf(gam) * __cosf((Th - qi)*0.5f) };
            f = cmul(f, fi);
        }
        {   // combine the two 4-factor halves
            c32 o2 = { __shfl_xor(f.x, 1), __shfl_xor(f.y, 1) };
            f = cmul(f, o2);
        }
        // compact: lane ln<32 grabs f for k=ln (lives at lane 2*ln)
        float fx = __shfl(f.x, 2*ln);
        float fy = __shfl(f.y, 2*ln);
        if (ln < 32) {
            const int kk = ln;
            float h7 = attn_param[15] * 0.5f;
            float s7 = __sinf(h7), c7 = __cosf(h7);
            c32 a0 = { -s7*fx, -s7*fy };
            c32 a1 = {  c7*fx,  c7*fy };
            c32 acc = a0;                      // backward inclusive product scan
            #pragma unroll
            for (int off = 1; off < 32; off <<= 1) {
                c32 v = { __shfl_down(acc.x, off), __shfl_down(acc.y, off) };
                if (kk + off < 32) acc = cmul(acc, v);
            }
            c32 S = { __shfl_down(acc.x, 1), __shfl_down(acc.y, 1) };
            if (kk == 31) { S.x = 1.f; S.y = 0.f; }
            c32 cf = cmul(S, a1);
            coefL[kk] = make_float2(cf.x, cf.y);
            if (kk == 0) coefL[32] = make_float2(acc.x, acc.y);  // total
        }
    }
    __syncthreads();                          // phase-1 LDS results visible

    if (t == 0) {
        // data-before-flag: sc1 store completion == global visibility
        asm volatile("s_waitcnt vmcnt(0)" ::: "memory");
        __hip_atomic_fetch_add(&g_ctr[b], 1u, __ATOMIC_RELAXED,
                               __HIP_MEMORY_SCOPE_SYSTEM);
        while (__hip_atomic_load(&g_ctr[b], __ATOMIC_RELAXED,
                                 __HIP_MEMORY_SCOPE_SYSTEM) < 32u)
            __builtin_amdgcn_s_sleep(4);
        asm volatile("" ::: "memory");        // no hoisting of vs loads above spin
    }
    __syncthreads();                          // batch b fully staged in L3

    // ================= phase 2: combine for (b, q=j) =================
    {
        const float2* vb = vs + ((size_t)b*16) * 512;   // b's panel (float2 units)
        c32 vn = { 0.f, 0.f };
        #pragma unroll
        for (int k2 = 0; k2 < 16; ++k2) {
            float2 va = ld_sys(vb + (size_t)(k2*256 + t)*2);      // k = 2*k2
            float2 vB = ld_sys(vb + (size_t)(k2*256 + t)*2 + 1);  // k = 2*k2+1
            float2 cfa = coefL[2*k2], cfb = coefL[2*k2 + 1];
            vn.x += cfa.x*va.x - cfa.y*va.y + cfb.x*vB.x - cfb.y*vB.y;
            vn.y += cfa.x*va.y + cfa.y*va.x + cfb.x*vB.y + cfb.y*vB.x;
        }
        if (t == 0) { vn.x += coefL[32].x; vn.y += coefL[32].y; }
        prob[t] = vn.x*vn.x + vn.y*vn.y;
    }
    __syncthreads();

    // sign expectation per wire
    {
        const int gg = t >> 5, l = t & 31;
        float sp = 0.f, ss = 0.f;
        #pragma unroll
        for (int j2 = 0; j2 < 8; ++j2) {
            int d2 = l + 32*j2;
            float p = prob[d2];
            sp += p;
            ss += ((d2 >> (7 - gg)) & 1) ? -p : p;
        }
        #pragma unroll
        for (int off = 1; off < 32; off <<= 1) {
            sp += __shfl_xor(sp, off);
            ss += __shfl_xor(ss, off);
        }
        if (l == 0) out[(b*NQ + j)*8 + gg] = ss / sp;
    }

    // ticket reset: 64th arrival (32 produce + 32 consume) restores g_ctr==0
    __syncthreads();
    if (t == 0) {
        unsigned old = __hip_atomic_fetch_add(&g_ctr[b], 1u, __ATOMIC_RELAXED,
                                              __HIP_MEMORY_SCOPE_SYSTEM);
        if (old == 63u)
            __hip_atomic_store(&g_ctr[b], 0u, __ATOMIC_RELAXED,
                               __HIP_MEMORY_SCOPE_SYSTEM);
    }
}

extern "C" void kernel_launch(void* const* d_in, const int* in_sizes, int n_in,
                              void* d_out, int out_size, void* d_ws, size_t ws_size,
                              hipStream_t stream) {
    const float* query      = (const float*)d_in[0];
    const float* key        = (const float*)d_in[1];
    const float* value      = (const float*)d_in[2];
    const float* v_param    = (const float*)d_in[3];
    const float* qk_param   = (const float*)d_in[4];
    const float* attn_param = (const float*)d_in[5];

    float2* vs  = (float2*)d_ws;             // 512 KB scratch (L3-resident)
    float*  out = (float*)d_out;

    fused_kernel<<<NB*NK, 256, 0, stream>>>(query, key, value, v_param,
                                            qk_param, attn_param, vs, out);
}

// Round 8
// 16.181 us; speedup vs baseline: 2.1560x; 1.3081x over previous
//
#include <hip/hip_runtime.h>
#include <math.h>

#define NB 8
#define NQ 32
#define NK 32
#define DIM 256

struct c32 { float x, y; };
__device__ __forceinline__ c32 cmul(c32 a, c32 b) {
    return { a.x*b.x - a.y*b.y, a.x*b.y + a.y*b.x };
}

// ---------------------------------------------------------------------------
// Compile-time GF(2) bookkeeping for the CNOT layers (verified rounds 3-7).
// ---------------------------------------------------------------------------
struct Maps { unsigned char m[6][8]; unsigned char r[6][8]; unsigned char fin[8]; };

constexpr unsigned gstep(int rep, unsigned y, int i) {
    int tgt = (i + 1 + rep) % 8;
    return y ^ (((y >> (7 - i)) & 1u) << (7 - tgt));
}
constexpr unsigned Lmap(int rep, unsigned x) {
    unsigned y = x;
    for (int i = 7; i >= 0; --i) y = gstep(rep, y, i);
    return y;
}
constexpr unsigned Linvmap(int rep, unsigned x) {
    unsigned y = x;
    for (int i = 0; i < 8; ++i) y = gstep(rep, y, i);
    return y;
}
constexpr Maps make_maps() {
    Maps mp{};
    unsigned Mc[8], Mic[8];
    for (int j2 = 0; j2 < 8; ++j2) { Mc[j2] = 1u << j2; Mic[j2] = 1u << j2; }
    for (int rep = 0; rep < 6; ++rep) {
        for (int bb = 0; bb < 8; ++bb) {
            mp.m[rep][bb] = (unsigned char)Mc[bb];
            unsigned row = 0;
            for (int k = 0; k < 8; ++k) row |= ((Mic[k] >> bb) & 1u) << k;
            mp.r[rep][bb] = (unsigned char)row;
        }
        unsigned nM[8], nMi[8];
        for (int j2 = 0; j2 < 8; ++j2) {
            unsigned v = Lmap(rep, 1u << j2), acc = 0;
            for (int k = 0; k < 8; ++k) if ((v >> k) & 1u) acc ^= Mc[k];
            nM[j2]  = acc;
            nMi[j2] = Linvmap(rep, Mic[j2]);
        }
        for (int j2 = 0; j2 < 8; ++j2) { Mc[j2] = nM[j2]; Mic[j2] = nMi[j2]; }
    }
    for (int j2 = 0; j2 < 8; ++j2) mp.fin[j2] = (unsigned char)Mic[j2];
    return mp;
}
constexpr Maps MAPS = make_maps();

// ---------------------------------------------------------------------------
// Fully block-local kernel. Block = (b = bid>>5, q = bid&31), 256 threads.
// Uses linearity: v_new[b,q] = W·(Σ_k coeff[k]·p(b,k)) + total·e0, where
// W = fixed post-initial-layer unitary of v_circuit and p = product states.
// So each block builds m = Σ_k coeff·p directly from inputs, runs the
// (verified) 48-gate chain once on m, and reduces. No inter-block traffic.
// ---------------------------------------------------------------------------
__global__ __launch_bounds__(256) void fused_kernel(
        const float* __restrict__ query, const float* __restrict__ key,
        const float* __restrict__ value, const float* __restrict__ v_param,
        const float* __restrict__ qk_param, const float* __restrict__ attn_param,
        float* __restrict__ out) {
    const int bid = blockIdx.x;
    const int b   = bid >> 5;
    const int q   = bid & 31;
    const int t   = threadIdx.x;
    const int wv  = t >> 6;
    const int ln  = t & 63;

    __shared__ float2 U[48][4];
    __shared__ float2 cs[32][8];     // (cos,sin) of value[b,k,i]/2
    __shared__ float2 a0s[32], a1s[32];
    __shared__ float2 coefL[33];     // [k]=suffix*a1, [32]=total
    __shared__ float2 pm[3][64][4];  // m partials from waves 1..3
    __shared__ float  prob[256];

    // ================= phase 1: tables, U, factors (all waves) =================
    {   // sincos table for value[b,k,i]
        const int k = t >> 3, i = t & 7;
        float sn, cn;
        __sincosf(value[(b*NK + k)*8 + i] * 0.5f, &sn, &cn);
        cs[k][i] = make_float2(cn, sn);
    }
    if (t < 48) {                    // U matrices (state-independent)
        int rep = t >> 3, w = t & 7;
        float a   = v_param[(rep*3 + 0)*8 + w];
        float bb2 = v_param[(rep*3 + 1)*8 + w];
        float c   = v_param[(rep*3 + 2)*8 + w];
        float sb, cb;     __sincosf(bb2*0.5f, &sb, &cb);
        float sapc, capc; __sincosf((a + c)*0.5f, &sapc, &capc);
        float samc, camc; __sincosf((a - c)*0.5f, &samc, &camc);
        U[t][0] = make_float2( cb*capc, -cb*sapc);
        U[t][1] = make_float2(-sb*camc, -sb*samc);
        U[t][2] = make_float2( sb*camc, -sb*samc);
        U[t][3] = make_float2( cb*capc,  cb*sapc);
    }
    {   // QK factor for (k = t>>3, i = t&7); 8-lane product reduce (verified r2)
        const int k = t >> 3, i = t & 7;
        float qi  = query[(b*NQ + q)*8 + i];
        float ki  = key[(b*NK + k)*8 + i];
        float phi = attn_param[i] + ((i > 0) ? attn_param[8 + i - 1] : 0.f);
        float Th  = phi + qk_param[8 + i] - ki;
        float gam = qk_param[i] * 0.5f;
        c32 f = {  __cosf(gam) * __cosf((Th + qi)*0.5f),
                  -__sinf(gam) * __cosf((Th - qi)*0.5f) };
        #pragma unroll
        for (int off = 1; off < 8; off <<= 1) {      // stays in 8-lane group
            c32 o2 = { __shfl_xor(f.x, off), __shfl_xor(f.y, off) };
            f = cmul(f, o2);
        }
        if (i == 0) {
            float h7 = attn_param[15] * 0.5f;
            float s7 = __sinf(h7), c7 = __cosf(h7);
            a0s[k] = make_float2(-s7*f.x, -s7*f.y);
            a1s[k] = make_float2( c7*f.x,  c7*f.y);
        }
    }
    __syncthreads();

    if (t < 32) {                    // suffix product scan (verified r5)
        const int kk = t;
        c32 a0 = { a0s[kk].x, a0s[kk].y };
        c32 a1 = { a1s[kk].x, a1s[kk].y };
        c32 acc = a0;
        #pragma unroll
        for (int off = 1; off < 32; off <<= 1) {
            c32 v = { __shfl_down(acc.x, off), __shfl_down(acc.y, off) };
            if (kk + off < 32) acc = cmul(acc, v);
        }
        c32 S = { __shfl_down(acc.x, 1), __shfl_down(acc.y, 1) };
        if (kk == 31) { S.x = 1.f; S.y = 0.f; }
        c32 cf = cmul(S, a1);
        coefL[kk] = make_float2(cf.x, cf.y);
        if (kk == 0) coefL[32] = make_float2(acc.x, acc.y);  // total
    }
    __syncthreads();

    // ================= phase 2: m = sum_k coeff[k] * p(b,k) ====================
    // lane ln holds d-bits 7..2; slot r holds bits 1..0 (wire6,7).
    float2 amp[4];
    #pragma unroll
    for (int r = 0; r < 4; ++r) amp[r] = make_float2(0.f, 0.f);
    #pragma unroll
    for (int kk2 = 0; kk2 < 8; ++kk2) {
        const int k = wv*8 + kk2;
        float common = 1.f;
        #pragma unroll
        for (int i = 0; i < 6; ++i) {
            float2 e = cs[k][i];                     // broadcast read
            common *= ((ln >> (5 - i)) & 1) ? e.y : e.x;
        }
        float2 e6 = cs[k][6], e7 = cs[k][7];
        float g0 = e6.x*e7.x, g1 = e6.x*e7.y, g2 = e6.y*e7.x, g3 = e6.y*e7.y;
        float2 cf = coefL[k];
        float G;
        G = common*g0; amp[0].x += cf.x*G; amp[0].y += cf.y*G;
        G = common*g1; amp[1].x += cf.x*G; amp[1].y += cf.y*G;
        G = common*g2; amp[2].x += cf.x*G; amp[2].y += cf.y*G;
        G = common*g3; amp[3].x += cf.x*G; amp[3].y += cf.y*G;
    }
    if (wv > 0) {
        #pragma unroll
        for (int r = 0; r < 4; ++r) pm[wv - 1][ln][r] = amp[r];
    }
    __syncthreads();

    if (wv == 0) {
        #pragma unroll
        for (int p = 0; p < 3; ++p)
            #pragma unroll
            for (int r = 0; r < 4; ++r) {
                float2 v = pm[p][ln][r];
                amp[r].x += v.x; amp[r].y += v.y;
            }

        // ============== phase 3: 48-gate chain on m (verified r3-r7) ==========
        #pragma unroll
        for (int rep = 0; rep < 6; ++rep) {
            #pragma unroll
            for (int w = 0; w < 8; ++w) {
                const int g = rep*8 + w;
                const unsigned mm = MAPS.m[rep][7 - w];
                const unsigned rb = MAPS.r[rep][7 - w];
                const unsigned lm = mm >> 2;
                const unsigned sm = mm & 3;
                const float2 u00 = U[g][0], u01 = U[g][1];
                const float2 u10 = U[g][2], u11 = U[g][3];
                float2 P[4];
                if (sm == 0)      { P[0]=amp[0]; P[1]=amp[1]; P[2]=amp[2]; P[3]=amp[3]; }
                else if (sm == 1) { P[0]=amp[1]; P[1]=amp[0]; P[2]=amp[3]; P[3]=amp[2]; }
                else if (sm == 2) { P[0]=amp[2]; P[1]=amp[3]; P[2]=amp[0]; P[3]=amp[1]; }
                else              { P[0]=amp[3]; P[1]=amp[2]; P[2]=amp[1]; P[3]=amp[0]; }
                if (lm) {
                    #pragma unroll
                    for (int r2 = 0; r2 < 4; ++r2) {
                        P[r2].x = __shfl_xor(P[r2].x, (int)lm);
                        P[r2].y = __shfl_xor(P[r2].y, (int)lm);
                    }
                }
                const unsigned hx = __popc((unsigned)(ln << 2) & rb) & 1u;
                float2 na[4];
                #pragma unroll
                for (int r2 = 0; r2 < 4; ++r2) {
                    const bool h = (hx ^ (__popc((unsigned)r2 & rb) & 1u)) != 0u;
                    const float2 uo = h ? u11 : u00;
                    const float2 up = h ? u10 : u01;
                    na[r2].x = uo.x*amp[r2].x - uo.y*amp[r2].y + up.x*P[r2].x - up.y*P[r2].y;
                    na[r2].y = uo.x*amp[r2].y + uo.y*amp[r2].x + up.x*P[r2].y + up.y*P[r2].x;
                }
                #pragma unroll
                for (int r2 = 0; r2 < 4; ++r2) amp[r2] = na[r2];
            }
        }

        // ============== phase 4: +total at logical 0; prob scatter ============
        if (ln == 0) {                        // stored (0,0) <-> logical 0
            amp[0].x += coefL[32].x;
            amp[0].y += coefL[32].y;
        }
        unsigned c0 = 0;
        #pragma unroll
        for (int kk = 0; kk < 6; ++kk)
            c0 ^= ((ln >> kk) & 1) ? (unsigned)MAPS.fin[kk + 2] : 0u;
        #pragma unroll
        for (int r2 = 0; r2 < 4; ++r2) {
            unsigned c = c0 ^ ((r2 & 1) ? (unsigned)MAPS.fin[0] : 0u)
                            ^ ((r2 & 2) ? (unsigned)MAPS.fin[1] : 0u);
            prob[c] = amp[r2].x*amp[r2].x + amp[r2].y*amp[r2].y;
        }
    }
    __syncthreads();

    // ================= phase 5: sign expectation per wire (verified r2) =======
    {
        const int gg = t >> 5, l = t & 31;
        float sp = 0.f, ss = 0.f;
        #pragma unroll
        for (int j2 = 0; j2 < 8; ++j2) {
            int d2 = l + 32*j2;
            float p = prob[d2];
            sp += p;
            ss += ((d2 >> (7 - gg)) & 1) ? -p : p;
        }
        #pragma unroll
        for (int off = 1; off < 32; off <<= 1) {
            sp += __shfl_xor(sp, off);
            ss += __shfl_xor(ss, off);
        }
        if (l == 0) out[(b*NQ + q)*8 + gg] = ss / sp;
    }
}

extern "C" void kernel_launch(void* const* d_in, const int* in_sizes, int n_in,
                              void* d_out, int out_size, void* d_ws, size_t ws_size,
                              hipStream_t stream) {
    const float* query      = (const float*)d_in[0];
    const float* key        = (const float*)d_in[1];
    const float* value      = (const float*)d_in[2];
    const float* v_param    = (const float*)d_in[3];
    const float* qk_param   = (const float*)d_in[4];
    const float* attn_param = (const float*)d_in[5];

    fused_kernel<<<NB*NQ, 256, 0, stream>>>(query, key, value, v_param,
                                            qk_param, attn_param, (float*)d_out);
}